// Round 6
// baseline (509.091 us; speedup 1.0000x reference)
//
#include <hip/hip_runtime.h>
#include <math.h>

#define N_NODES 50000
#define N_EDGES 800000
#define DIM_IN 64
#define DIM_HID 128
#define DIM_OUT 64
#define PAD 136   // bf16 per weight row: 272B, 16B-aligned

typedef __attribute__((ext_vector_type(8))) short short8;   // 8 bf16 (4 VGPRs)
typedef __attribute__((ext_vector_type(4))) float f32x4;    // MFMA accumulator

union U8 { uint4 u; short8 s; };

// RTNE float->bf16 (inputs finite) -- software path, used only in weight prep
__device__ __forceinline__ unsigned short f2bf(float f) {
    unsigned u = __float_as_uint(f);
    return (unsigned short)((u + 0x7fffu + ((u >> 16) & 1u)) >> 16);
}

// gfx950 has NO cvt_pk_bf16 builtin (learn_hip m240). Single VOP3 via asm.
// lo = a, hi = b; RTNE (default round mode) == the software f2bf path.
__device__ __forceinline__ unsigned cvt_pk_bf16(float a, float b) {
    unsigned d;
    asm("v_cvt_pk_bf16_f32 %0, %1, %2" : "=v"(d) : "v"(a), "v"(b));
    return d;
}

__device__ __forceinline__ float exp2_fast(float a) {
#if __has_builtin(__builtin_amdgcn_exp2f)
    return __builtin_amdgcn_exp2f(a);
#else
    return __expf(a * 0.69314718f);
#endif
}

// softplus(x) = max(x,0) + log1p(exp(-|x|)); log1p(z) ~ z*(1 + z*(-0.5 + z*(A + z*B)))
// cubic fit on z in (0,1], max abs err ~1.5e-3 (below bf16 quantization of H)
__device__ __forceinline__ unsigned sp2(float x0, float x1) {
    const float L2E = 1.44269504f;
    float z0 = exp2_fast(-fabsf(x0) * L2E);
    float z1 = exp2_fast(-fabsf(x1) * L2E);
    float p0 = fmaf(fmaf(fmaf(-0.1011458f, z0, 0.2942925f), z0, -0.5f), z0, 1.0f) * z0;
    float p1 = fmaf(fmaf(fmaf(-0.1011458f, z1, 0.2942925f), z1, -0.5f), z1, 1.0f) * z1;
    return cvt_pk_bf16(fmaxf(x0, 0.0f) + p0, fmaxf(x1, 0.0f) + p1);
}

// Prep: convert x to a bf16 table (optional) + build bf16 W^T [n][PAD] tables
// (layers 1,2 carry the K-permutation pi matching the MFMA C-layout -> frag
// renaming). Output zeroing is a separate hipMemsetAsync (DMA path -- measured
// cheaper than a CS zero-fill fused here: R0 gap ~50us vs R1 gap ~69us).
template <bool DO_XBF>
__global__ void prep_all(const float* __restrict__ x,
                         const float* __restrict__ W0,
                         const float* __restrict__ W1,
                         const float* __restrict__ W2,
                         unsigned short* __restrict__ wt,
                         unsigned short* __restrict__ xbf) {
    int i = blockIdx.x * blockDim.x + threadIdx.x;

    if (DO_XBF && i < (N_NODES * DIM_IN / 4)) {      // 800000 float4 -> uint2 bf16
        float4 v = *((const float4*)x + i);
        uint2 p;
        p.x = cvt_pk_bf16(v.x, v.y);
        p.y = cvt_pk_bf16(v.z, v.w);
        *((uint2*)xbf + i) = p;
    }

    if (i < 320 * PAD) {                             // 43520 weight elements
        int row = i / PAD, s = i - row * PAD;
        float v = 0.f;
        if (s < 128) {
            int f = ((s >> 5) << 5) | (((s & 7) >> 2) << 4) | (((s >> 3) & 3) << 2) | (s & 3);
            if (row < 128)      v = W0[s * DIM_HID + row];          // layer 0: natural k
            else if (row < 256) v = W1[f * DIM_HID + (row - 128)];  // layer 1: permuted k
            else                v = W2[f * DIM_OUT + (row - 256)];  // layer 2: permuted k
        }
        wt[i] = f2bf(v);
    }
}

// Layers 0,1 flipped: H^T = softplus(W^T H^T + b) via mfma(A=weight, B=activation).
// Layer 2 un-flipped: O = H W2 + b2 via mfma(A=activation, B=weight); C row=edge.
//
// Occupancy round (re-run; round-5 bench was an infra failure, kernel audited
// clean): R4's 34,816B LDS capped us at 4 blocks/CU (achieved occ 40%); wave
// residency arithmetic (25us/wave for ~2k insts = ~30 cy/inst) says the kernel
// is latency-bound with too few waves to cover dependency chains. Weights
// staged in FIVE 64-row chunks (17,408B buffer): L0 = chunks 0,1; L1 = chunks
// 2,3; L2 = chunk 4 (its table is exactly 64 rows). 17,408B/block -> 8
// blocks/CU -> 2048 threads = 100% theoretical occupancy.
// __launch_bounds__(256,8) caps VGPR at 64 (R4 compiled to 60 under a 128 cap).
template <bool XB>
__global__ __launch_bounds__(256, 8)
void edge_mlp_mfma(const float* __restrict__ x,
                   const unsigned short* __restrict__ xbf,
                   const int* __restrict__ eidx,
                   const unsigned short* __restrict__ wt,
                   const float* __restrict__ b0,
                   const float* __restrict__ b1,
                   const float* __restrict__ b2,
                   float* __restrict__ out) {
    __shared__ unsigned short lw[64 * PAD];   // 17,408 B: one 64-row weight chunk

    const int lane = threadIdx.x & 63;
    const int w    = threadIdx.x >> 6;
    const int l16  = lane & 15;
    const int q    = lane >> 4;
    const int e0w  = blockIdx.x * 128 + w * 32;   // this wave's 32 edges

    int nodeR[2], nodeC[2];
#pragma unroll
    for (int m = 0; m < 2; ++m) {
        nodeR[m] = eidx[e0w + m * 16 + l16];
        nodeC[m] = eidx[N_EDGES + e0w + m * 16 + l16];
    }

    // layer-2 scatter nodes for this quad's 8 edges (L1-hot reload)
    int ns[8];
#pragma unroll
    for (int m = 0; m < 2; ++m)
#pragma unroll
        for (int r = 0; r < 4; ++r)
            ns[m * 4 + r] = eidx[e0w + m * 16 + q * 4 + r];

    // layer-0 B-frags: B(k=kk*32+q*8+j, edge=m*16+l16) -- issued before the
    // first stage+barrier so gather latency hides under them
    short8 hfr[2][4];
#pragma unroll
    for (int m = 0; m < 2; ++m)
#pragma unroll
        for (int kk = 0; kk < 4; ++kk) {
            int node = (kk >= 2) ? nodeC[m] : nodeR[m];
            if (XB) {
                hfr[m][kk] = *(const short8*)(xbf + (size_t)node * DIM_IN + (kk & 1) * 32 + q * 8);
            } else {
                const float* p = x + (size_t)node * DIM_IN + (kk & 1) * 32 + q * 8;
                float4 v0 = *(const float4*)p;
                float4 v1 = *(const float4*)(p + 4);
                U8 t;
                t.u.x = cvt_pk_bf16(v0.x, v0.y);
                t.u.y = cvt_pk_bf16(v0.z, v0.w);
                t.u.z = cvt_pk_bf16(v1.x, v1.y);
                t.u.w = cvt_pk_bf16(v1.z, v1.w);
                hfr[m][kk] = t.s;
            }
        }

    // stage chunk 0 (weight rows 0..63): 1088 uint4, coalesced
    {
        const uint4* src = (const uint4*)wt;
        uint4* dst = (uint4*)lw;
#pragma unroll
        for (int it = 0; it < 5; ++it) {
            int i = threadIdx.x + it * 256;
            if (i < 1088) dst[i] = src[i];
        }
    }
    __syncthreads();

    // ---- layers 0,1: H^T = softplus(W^T H^T + b), weights from LDS chunks ----
#pragma unroll
    for (int L = 0; L < 2; ++L) {
        const float* bias = L ? b1 : b0;
        unsigned d[2][8][2];
#pragma unroll
        for (int half = 0; half < 2; ++half) {
#pragma unroll
            for (int ti = 0; ti < 4; ++ti) {
                const int tiG = half * 4 + ti;
                f32x4 bb = *(const f32x4*)(bias + tiG * 16 + q * 4);  // bias on row dim
                f32x4 a0 = bb, a1 = bb;
                const unsigned short* Wp = lw + (ti * 16 + l16) * PAD + q * 8;
                short8 wf[4];
#pragma unroll
                for (int kk = 0; kk < 4; ++kk)
                    wf[kk] = *(const short8*)(Wp + kk * 32);          // ds_read_b128
#pragma unroll
                for (int kk = 0; kk < 4; ++kk) {
                    a0 = __builtin_amdgcn_mfma_f32_16x16x32_bf16(wf[kk], hfr[0][kk], a0, 0, 0, 0);
                    a1 = __builtin_amdgcn_mfma_f32_16x16x32_bf16(wf[kk], hfr[1][kk], a1, 0, 0, 0);
                }
                // per-ti epilogue keeps acc liveness at 8 VGPRs
                d[0][tiG][0] = sp2(a0[0], a0[1]);
                d[0][tiG][1] = sp2(a0[2], a0[3]);
                d[1][tiG][0] = sp2(a1[0], a1[1]);
                d[1][tiG][1] = sp2(a1[2], a1[3]);
            }
            // swap in the next 64-row chunk (the last one is L2's table)
            __syncthreads();                  // all waves done reading lw
            {
                const uint4* src = (const uint4*)(wt + (size_t)(L * 2 + half + 1) * 64 * PAD);
                uint4* dst = (uint4*)lw;
#pragma unroll
                for (int it = 0; it < 5; ++it) {
                    int i = threadIdx.x + it * 256;
                    if (i < 1088) dst[i] = src[i];
                }
            }
            __syncthreads();
        }
        // next-layer frags: pure register renaming (weights carry pi)
#pragma unroll
        for (int m = 0; m < 2; ++m)
#pragma unroll
            for (int kk = 0; kk < 4; ++kk) {
                U8 t;
                t.u.x = d[m][2 * kk][0];
                t.u.y = d[m][2 * kk][1];
                t.u.z = d[m][2 * kk + 1][0];
                t.u.w = d[m][2 * kk + 1][1];
                hfr[m][kk] = t.s;
            }
    }

    // ---- layer 2 (un-flipped): O = H W2 + b2; lw holds chunk 4 (rows 256..319).
    // All loads complete before any atomic issues (vmcnt is in-order).
    {
        f32x4 acc[4][2];
#pragma unroll
        for (int ti = 0; ti < 4; ++ti) {
            float bv = b2[ti * 16 + l16];                    // bias on col dim
            f32x4 a0 = (f32x4){bv, bv, bv, bv};
            f32x4 a1 = a0;
            const unsigned short* Wp = lw + (ti * 16 + l16) * PAD + q * 8;
            short8 wf[4];
#pragma unroll
            for (int kk = 0; kk < 4; ++kk)
                wf[kk] = *(const short8*)(Wp + kk * 32);      // ds_read_b128
#pragma unroll
            for (int kk = 0; kk < 4; ++kk) {
                a0 = __builtin_amdgcn_mfma_f32_16x16x32_bf16(hfr[0][kk], wf[kk], a0, 0, 0, 0);
                a1 = __builtin_amdgcn_mfma_f32_16x16x32_bf16(hfr[1][kk], wf[kk], a1, 0, 0, 0);
            }
            acc[ti][0] = a0;
            acc[ti][1] = a1;
        }

        // terminal atomic burst: fire-and-forget, nothing waits on the acks.
        // each instruction covers full 64B sectors (quad-uniform node, l16 lanes
        // contiguous), 4 transactions/instr.
#pragma unroll
        for (int ti = 0; ti < 4; ++ti)
#pragma unroll
            for (int r = 0; r < 4; ++r) {
                atomicAdd(out + (size_t)ns[r] * DIM_OUT + ti * 16 + l16, acc[ti][0][r]);
                atomicAdd(out + (size_t)ns[4 + r] * DIM_OUT + ti * 16 + l16, acc[ti][1][r]);
            }
    }
}

extern "C" void kernel_launch(void* const* d_in, const int* in_sizes, int n_in,
                              void* d_out, int out_size, void* d_ws, size_t ws_size,
                              hipStream_t stream) {
    const float* x  = (const float*)d_in[0];
    const int*   ei = (const int*)d_in[1];
    const float* W0 = (const float*)d_in[2];
    const float* b0 = (const float*)d_in[3];
    const float* W1 = (const float*)d_in[4];
    const float* b1 = (const float*)d_in[5];
    const float* W2 = (const float*)d_in[6];
    const float* b2 = (const float*)d_in[7];
    float* out = (float*)d_out;

    unsigned short* wt = (unsigned short*)d_ws;
    const size_t WT_BYTES = (size_t)320 * PAD * sizeof(unsigned short);  // 87040 (256-aligned)
    unsigned short* xbf = (unsigned short*)((char*)d_ws + WT_BYTES);
    const size_t need = WT_BYTES + (size_t)N_NODES * DIM_IN * sizeof(unsigned short); // ~6.5 MB

    hipMemsetAsync(out, 0, (size_t)N_NODES * DIM_OUT * sizeof(float), stream);

    if (ws_size >= need) {
        prep_all<true><<<(N_NODES * DIM_IN / 4 + 255) / 256, 256, 0, stream>>>(
            x, W0, W1, W2, wt, xbf);
        edge_mlp_mfma<true><<<N_EDGES / 128, 256, 0, stream>>>(
            x, xbf, ei, wt, b0, b1, b2, out);
    } else {
        // fallback: weights-only prep, f32 x gather
        prep_all<false><<<(320 * PAD + 255) / 256, 256, 0, stream>>>(
            x, W0, W1, W2, wt, nullptr);
        edge_mlp_mfma<false><<<N_EDGES / 128, 256, 0, stream>>>(
            x, nullptr, ei, wt, b0, b1, b2, out);
    }
}

// Round 7
// 394.925 us; speedup vs baseline: 1.2891x; 1.2891x over previous
//
#include <hip/hip_runtime.h>
#include <math.h>

#define N_NODES 50000
#define N_EDGES 800000
#define DIM_IN 64
#define DIM_HID 128
#define DIM_OUT 64
#define WROW 128   // bf16 per weight row: 256B exactly (no pad; XOR swizzle handles banks)

typedef __attribute__((ext_vector_type(8))) short short8;   // 8 bf16 (4 VGPRs)
typedef __attribute__((ext_vector_type(4))) float f32x4;    // MFMA accumulator

union U8 { uint4 u; short8 s; };

// RTNE float->bf16 (inputs finite) -- software path, used only in weight prep
__device__ __forceinline__ unsigned short f2bf(float f) {
    unsigned u = __float_as_uint(f);
    return (unsigned short)((u + 0x7fffu + ((u >> 16) & 1u)) >> 16);
}

// gfx950 has NO cvt_pk_bf16 builtin (learn_hip m240). Single VOP3 via asm.
// lo = a, hi = b; RTNE (default round mode) == the software f2bf path.
__device__ __forceinline__ unsigned cvt_pk_bf16(float a, float b) {
    unsigned d;
    asm("v_cvt_pk_bf16_f32 %0, %1, %2" : "=v"(d) : "v"(a), "v"(b));
    return d;
}

__device__ __forceinline__ float exp2_fast(float a) {
#if __has_builtin(__builtin_amdgcn_exp2f)
    return __builtin_amdgcn_exp2f(a);
#else
    return __expf(a * 0.69314718f);
#endif
}

// softplus(x) = max(x,0) + log1p(exp(-|x|)); log1p(z) ~ z*(1 + z*(-0.5 + z*(A + z*B)))
// cubic fit on z in (0,1], max abs err ~1.5e-3 (below bf16 quantization of H)
__device__ __forceinline__ unsigned sp2(float x0, float x1) {
    const float L2E = 1.44269504f;
    float z0 = exp2_fast(-fabsf(x0) * L2E);
    float z1 = exp2_fast(-fabsf(x1) * L2E);
    float p0 = fmaf(fmaf(fmaf(-0.1011458f, z0, 0.2942925f), z0, -0.5f), z0, 1.0f) * z0;
    float p1 = fmaf(fmaf(fmaf(-0.1011458f, z1, 0.2942925f), z1, -0.5f), z1, 1.0f) * z1;
    return cvt_pk_bf16(fmaxf(x0, 0.0f) + p0, fmaxf(x1, 0.0f) + p1);
}

// Prep: convert x to a bf16 table (optional) + build bf16 W^T [320][128] table
// (layers 1,2 carry the K-permutation pi matching the MFMA C-layout -> frag
// renaming). Output zeroing is a separate hipMemsetAsync (DMA path).
template <bool DO_XBF>
__global__ void prep_all(const float* __restrict__ x,
                         const float* __restrict__ W0,
                         const float* __restrict__ W1,
                         const float* __restrict__ W2,
                         unsigned short* __restrict__ wt,
                         unsigned short* __restrict__ xbf) {
    int i = blockIdx.x * blockDim.x + threadIdx.x;

    if (DO_XBF && i < (N_NODES * DIM_IN / 4)) {      // 800000 float4 -> uint2 bf16
        float4 v = *((const float4*)x + i);
        uint2 p;
        p.x = cvt_pk_bf16(v.x, v.y);
        p.y = cvt_pk_bf16(v.z, v.w);
        *((uint2*)xbf + i) = p;
    }

    if (i < 320 * WROW) {                            // 40960 weight elements
        int row = i >> 7, s = i & 127;
        float v;
        int f = ((s >> 5) << 5) | (((s & 7) >> 2) << 4) | (((s >> 3) & 3) << 2) | (s & 3);
        if (row < 128)      v = W0[s * DIM_HID + row];          // layer 0: natural k
        else if (row < 256) v = W1[f * DIM_HID + (row - 128)];  // layer 1: permuted k
        else                v = W2[f * DIM_OUT + (row - 256)];  // layer 2: permuted k
        wt[i] = f2bf(v);
    }
}

// Layers 0,1 flipped: H^T = softplus(W^T H^T + b) via mfma(A=weight, B=activation).
// Layer 2 un-flipped: O = H W2 + b2 via mfma(A=activation, B=weight); C row=edge.
//
// THIS ROUND:
//  (a) __launch_bounds__(256,6): R6's (256,8) forced VGPR=32 -> ~1.6GB scratch
//      spill (FETCH 835MB / WRITE 974MB). (256,6) caps at ~84 regs -- room for
//      the measured ~60 arch VGPRs AND 6 blocks/CU (vs R4's 4).
//  (b) LDS weight chunks 64 rows x 256B = 16,384B (WROW=128, no pad) with an
//      XOR bank swizzle: 16B slot s of row r stored at s ^ (r&7). Read lanes
//      (l16,q) at fixed kk hit bank-group (4kk+q)^(l16&7) -> uniform 8
//      lanes/group = width-limited minimum (R4/R6 measured 8M conflict cycles
//      with the linear layout). Staging writes: 16 threads/row cover 16
//      distinct slots -> 2 dwords/bank = free (m136).
template <bool XB>
__global__ __launch_bounds__(256, 6)
void edge_mlp_mfma(const float* __restrict__ x,
                   const unsigned short* __restrict__ xbf,
                   const int* __restrict__ eidx,
                   const unsigned short* __restrict__ wt,
                   const float* __restrict__ b0,
                   const float* __restrict__ b1,
                   const float* __restrict__ b2,
                   float* __restrict__ out) {
    __shared__ unsigned short lw[64 * WROW];   // 16,384 B: one 64-row weight chunk

    const int lane = threadIdx.x & 63;
    const int w    = threadIdx.x >> 6;
    const int l16  = lane & 15;
    const int q    = lane >> 4;
    const int sx   = l16 & 7;                  // read-side swizzle key
    const int e0w  = blockIdx.x * 128 + w * 32;   // this wave's 32 edges

    int nodeR[2], nodeC[2];
#pragma unroll
    for (int m = 0; m < 2; ++m) {
        nodeR[m] = eidx[e0w + m * 16 + l16];
        nodeC[m] = eidx[N_EDGES + e0w + m * 16 + l16];
    }

    // layer-2 scatter nodes for this quad's 8 edges (L1-hot reload)
    int ns[8];
#pragma unroll
    for (int m = 0; m < 2; ++m)
#pragma unroll
        for (int r = 0; r < 4; ++r)
            ns[m * 4 + r] = eidx[e0w + m * 16 + q * 4 + r];

    // layer-0 B-frags: B(k=kk*32+q*8+j, edge=m*16+l16) -- issued before the
    // first stage+barrier so gather latency hides under them
    short8 hfr[2][4];
#pragma unroll
    for (int m = 0; m < 2; ++m)
#pragma unroll
        for (int kk = 0; kk < 4; ++kk) {
            int node = (kk >= 2) ? nodeC[m] : nodeR[m];
            if (XB) {
                hfr[m][kk] = *(const short8*)(xbf + (size_t)node * DIM_IN + (kk & 1) * 32 + q * 8);
            } else {
                const float* p = x + (size_t)node * DIM_IN + (kk & 1) * 32 + q * 8;
                float4 v0 = *(const float4*)p;
                float4 v1 = *(const float4*)(p + 4);
                U8 t;
                t.u.x = cvt_pk_bf16(v0.x, v0.y);
                t.u.y = cvt_pk_bf16(v0.z, v0.w);
                t.u.z = cvt_pk_bf16(v1.x, v1.y);
                t.u.w = cvt_pk_bf16(v1.z, v1.w);
                hfr[m][kk] = t.s;
            }
        }

    // stage chunk c (weight rows c*64..c*64+63): 1024 uint4 = 4 exact rounds.
    // LDS slot-swizzled: source 16B-slot col of row goes to col ^ (row&7).
    auto stage = [&](int c) {
        const uint4* src = (const uint4*)(wt + (size_t)c * 64 * WROW);
        uint4* dst = (uint4*)lw;
#pragma unroll
        for (int it = 0; it < 4; ++it) {
            int i = threadIdx.x + it * 256;        // 0..1023
            int row = i >> 4, col = i & 15;
            dst[row * 16 + (col ^ (row & 7))] = src[i];
        }
    };

    stage(0);
    __syncthreads();

    // ---- layers 0,1: H^T = softplus(W^T H^T + b), weights from LDS chunks ----
#pragma unroll
    for (int L = 0; L < 2; ++L) {
        const float* bias = L ? b1 : b0;
        unsigned d[2][8][2];
#pragma unroll
        for (int half = 0; half < 2; ++half) {
#pragma unroll
            for (int ti = 0; ti < 4; ++ti) {
                const int tiG = half * 4 + ti;
                f32x4 bb = *(const f32x4*)(bias + tiG * 16 + q * 4);  // bias on row dim
                f32x4 a0 = bb, a1 = bb;
                const unsigned short* rowb = lw + (ti * 16 + l16) * WROW;
                short8 wf[4];
#pragma unroll
                for (int kk = 0; kk < 4; ++kk)
                    wf[kk] = *(const short8*)(rowb + ((kk * 4 + q) ^ sx) * 8); // ds_read_b128, swizzled slot
#pragma unroll
                for (int kk = 0; kk < 4; ++kk) {
                    a0 = __builtin_amdgcn_mfma_f32_16x16x32_bf16(wf[kk], hfr[0][kk], a0, 0, 0, 0);
                    a1 = __builtin_amdgcn_mfma_f32_16x16x32_bf16(wf[kk], hfr[1][kk], a1, 0, 0, 0);
                }
                // per-ti epilogue keeps acc liveness at 8 VGPRs
                d[0][tiG][0] = sp2(a0[0], a0[1]);
                d[0][tiG][1] = sp2(a0[2], a0[3]);
                d[1][tiG][0] = sp2(a1[0], a1[1]);
                d[1][tiG][1] = sp2(a1[2], a1[3]);
            }
            // swap in the next 64-row chunk (the last one is L2's table)
            __syncthreads();                  // all waves done reading lw
            stage(L * 2 + half + 1);
            __syncthreads();
        }
        // next-layer frags: pure register renaming (weights carry pi)
#pragma unroll
        for (int m = 0; m < 2; ++m)
#pragma unroll
            for (int kk = 0; kk < 4; ++kk) {
                U8 t;
                t.u.x = d[m][2 * kk][0];
                t.u.y = d[m][2 * kk][1];
                t.u.z = d[m][2 * kk + 1][0];
                t.u.w = d[m][2 * kk + 1][1];
                hfr[m][kk] = t.s;
            }
    }

    // ---- layer 2 (un-flipped): O = H W2 + b2; lw holds chunk 4 (rows 256..319).
    // All loads complete before any atomic issues (vmcnt is in-order).
    {
        f32x4 acc[4][2];
#pragma unroll
        for (int ti = 0; ti < 4; ++ti) {
            float bv = b2[ti * 16 + l16];                    // bias on col dim
            f32x4 a0 = (f32x4){bv, bv, bv, bv};
            f32x4 a1 = a0;
            const unsigned short* rowb = lw + (ti * 16 + l16) * WROW;
            short8 wf[4];
#pragma unroll
            for (int kk = 0; kk < 4; ++kk)
                wf[kk] = *(const short8*)(rowb + ((kk * 4 + q) ^ sx) * 8);  // ds_read_b128, swizzled
#pragma unroll
            for (int kk = 0; kk < 4; ++kk) {
                a0 = __builtin_amdgcn_mfma_f32_16x16x32_bf16(hfr[0][kk], wf[kk], a0, 0, 0, 0);
                a1 = __builtin_amdgcn_mfma_f32_16x16x32_bf16(hfr[1][kk], wf[kk], a1, 0, 0, 0);
            }
            acc[ti][0] = a0;
            acc[ti][1] = a1;
        }

        // terminal atomic burst: fire-and-forget, nothing waits on the acks.
        // each instruction covers full 64B sectors (quad-uniform node, l16 lanes
        // contiguous), 4 transactions/instr.
#pragma unroll
        for (int ti = 0; ti < 4; ++ti)
#pragma unroll
            for (int r = 0; r < 4; ++r) {
                atomicAdd(out + (size_t)ns[r] * DIM_OUT + ti * 16 + l16, acc[ti][0][r]);
                atomicAdd(out + (size_t)ns[4 + r] * DIM_OUT + ti * 16 + l16, acc[ti][1][r]);
            }
    }
}

extern "C" void kernel_launch(void* const* d_in, const int* in_sizes, int n_in,
                              void* d_out, int out_size, void* d_ws, size_t ws_size,
                              hipStream_t stream) {
    const float* x  = (const float*)d_in[0];
    const int*   ei = (const int*)d_in[1];
    const float* W0 = (const float*)d_in[2];
    const float* b0 = (const float*)d_in[3];
    const float* W1 = (const float*)d_in[4];
    const float* b1 = (const float*)d_in[5];
    const float* W2 = (const float*)d_in[6];
    const float* b2 = (const float*)d_in[7];
    float* out = (float*)d_out;

    unsigned short* wt = (unsigned short*)d_ws;
    const size_t WT_BYTES = (size_t)320 * WROW * sizeof(unsigned short);  // 81920 (256-aligned)
    unsigned short* xbf = (unsigned short*)((char*)d_ws + WT_BYTES);
    const size_t need = WT_BYTES + (size_t)N_NODES * DIM_IN * sizeof(unsigned short); // ~6.5 MB

    hipMemsetAsync(out, 0, (size_t)N_NODES * DIM_OUT * sizeof(float), stream);

    if (ws_size >= need) {
        prep_all<true><<<(N_NODES * DIM_IN / 4 + 255) / 256, 256, 0, stream>>>(
            x, W0, W1, W2, wt, xbf);
        edge_mlp_mfma<true><<<N_EDGES / 128, 256, 0, stream>>>(
            x, xbf, ei, wt, b0, b1, b2, out);
    } else {
        // fallback: weights-only prep, f32 x gather
        prep_all<false><<<(320 * WROW + 255) / 256, 256, 0, stream>>>(
            x, W0, W1, W2, wt, nullptr);
        edge_mlp_mfma<false><<<N_EDGES / 128, 256, 0, stream>>>(
            x, nullptr, ei, wt, b0, b1, b2, out);
    }
}

// Round 8
// 313.254 us; speedup vs baseline: 1.6252x; 1.2607x over previous
//
#include <hip/hip_runtime.h>
#include <math.h>

#define N_NODES 50000
#define N_EDGES 800000
#define DIM_IN 64
#define DIM_HID 128
#define DIM_OUT 64
#define WROW 128          // bf16 per weight row: 256B (XOR swizzle handles banks)
#define NTILES (N_EDGES / 32)   // 25000 wave-tiles of 32 edges
#define GRID 512                // 2 blocks/CU * 256 CU
#define NWAVES (GRID * 8)       // 4096 persistent waves

typedef __attribute__((ext_vector_type(8))) short short8;   // 8 bf16 (4 VGPRs)
typedef __attribute__((ext_vector_type(4))) float f32x4;    // MFMA accumulator

union U8 { uint4 u; short8 s; };

// RTNE float->bf16 (inputs finite) -- software path, used only in weight prep
__device__ __forceinline__ unsigned short f2bf(float f) {
    unsigned u = __float_as_uint(f);
    return (unsigned short)((u + 0x7fffu + ((u >> 16) & 1u)) >> 16);
}

// gfx950 has NO cvt_pk_bf16 builtin (learn_hip m240). Single VOP3 via asm.
// lo = a, hi = b; RTNE (default round mode) == the software f2bf path.
__device__ __forceinline__ unsigned cvt_pk_bf16(float a, float b) {
    unsigned d;
    asm("v_cvt_pk_bf16_f32 %0, %1, %2" : "=v"(d) : "v"(a), "v"(b));
    return d;
}

__device__ __forceinline__ float exp2_fast(float a) {
#if __has_builtin(__builtin_amdgcn_exp2f)
    return __builtin_amdgcn_exp2f(a);
#else
    return __expf(a * 0.69314718f);
#endif
}

// softplus(x) = max(x,0) + log1p(exp(-|x|)); log1p(z) ~ z*(1 + z*(-0.5 + z*(A + z*B)))
// cubic fit on z in (0,1], max abs err ~1.5e-3 (below bf16 quantization of H)
__device__ __forceinline__ unsigned sp2(float x0, float x1) {
    const float L2E = 1.44269504f;
    float z0 = exp2_fast(-fabsf(x0) * L2E);
    float z1 = exp2_fast(-fabsf(x1) * L2E);
    float p0 = fmaf(fmaf(fmaf(-0.1011458f, z0, 0.2942925f), z0, -0.5f), z0, 1.0f) * z0;
    float p1 = fmaf(fmaf(fmaf(-0.1011458f, z1, 0.2942925f), z1, -0.5f), z1, 1.0f) * z1;
    return cvt_pk_bf16(fmaxf(x0, 0.0f) + p0, fmaxf(x1, 0.0f) + p1);
}

// Prep: convert x to a bf16 table (optional) + build bf16 W^T [320][128] table
// (layers 1,2 carry the K-permutation pi matching the MFMA C-layout -> frag
// renaming). Output zeroing is a separate hipMemsetAsync (DMA path).
template <bool DO_XBF>
__global__ void prep_all(const float* __restrict__ x,
                         const float* __restrict__ W0,
                         const float* __restrict__ W1,
                         const float* __restrict__ W2,
                         unsigned short* __restrict__ wt,
                         unsigned short* __restrict__ xbf) {
    int i = blockIdx.x * blockDim.x + threadIdx.x;

    if (DO_XBF && i < (N_NODES * DIM_IN / 4)) {      // 800000 float4 -> uint2 bf16
        float4 v = *((const float4*)x + i);
        uint2 p;
        p.x = cvt_pk_bf16(v.x, v.y);
        p.y = cvt_pk_bf16(v.z, v.w);
        *((uint2*)xbf + i) = p;
    }

    if (i < 320 * WROW) {                            // 40960 weight elements
        int row = i >> 7, s = i & 127;
        float v;
        int f = ((s >> 5) << 5) | (((s & 7) >> 2) << 4) | (((s >> 3) & 3) << 2) | (s & 3);
        if (row < 128)      v = W0[s * DIM_HID + row];          // layer 0: natural k
        else if (row < 256) v = W1[f * DIM_HID + (row - 128)];  // layer 1: permuted k
        else                v = W2[f * DIM_OUT + (row - 256)];  // layer 2: permuted k
        wt[i] = f2bf(v);
    }
}

// PERSISTENT edge-MLP. Layers 0,1 flipped: H^T = softplus(W^T H^T + b) via
// mfma(A=weight, B=activation). Layer 2 un-flipped: O = H W2 + b2.
//
// Structure rationale (R4-R7 evidence): dur floor ~190us was invariant under
// fetch/atomic/weight-path diets; launch-bounds > 4 blk/CU spills (VGPR cap);
// bottom-up latency math says dependency chains at 4 waves/SIMD cost only
// ~20-40us -> the floor is block-serial overhead: 6250 blocks x {re-stage 87KB
// + 6 lockstep barriers}. Fix: 512 persistent blocks (2/CU, 16 waves/CU = R4's
// TLP), stage L0+L1 (65,536B LDS, static max) ONCE, one barrier, then each
// wave independently processes 6-7 tiles of 32 edges -- no barriers, waves
// drift out of phase so shared pipes (LDS/TA/VALU/MFMA) interleave.
// L2 table (16KB) + biases stay in L1-hot global. Next tile's gathers are
// issued BEFORE the atomic burst (in-order vmcnt: loads issued after atomics
// can't complete until all atomic acks return).
template <bool XB>
__global__ __launch_bounds__(512, 4)
void edge_mlp_mfma(const float* __restrict__ x,
                   const unsigned short* __restrict__ xbf,
                   const int* __restrict__ eidx,
                   const unsigned short* __restrict__ wt,
                   const float* __restrict__ b0,
                   const float* __restrict__ b1,
                   const float* __restrict__ b2,
                   float* __restrict__ out) {
    __shared__ unsigned short lw[256 * WROW];   // 65,536 B: L0+L1 tables

    const int lane = threadIdx.x & 63;
    const int w    = threadIdx.x >> 6;          // 0..7
    const int l16  = lane & 15;
    const int q    = lane >> 4;
    const int sx   = l16 & 7;                   // read-side swizzle key
    const int gwid = blockIdx.x * 8 + w;        // 0..4095

    // stage L0+L1 (rows 0..255): 4096 uint4, swizzled: 16B-slot col -> col^(row&7)
    {
        const uint4* src = (const uint4*)wt;
        uint4* dst = (uint4*)lw;
#pragma unroll
        for (int it = 0; it < 8; ++it) {
            int i = threadIdx.x + it * 512;
            int row = i >> 4, col = i & 15;
            dst[(row << 4) | (col ^ (row & 7))] = src[i];
        }
    }
    __syncthreads();   // the ONLY barrier in this kernel

    const unsigned short* Wt2 = wt + 256 * WROW;   // L2 table: global, L1-hot

    // tile loader: edge indices + layer-0 B-frags B(k=kk*32+q*8+j, edge=m*16+l16)
    auto load_tile = [&](int t, int (&nsv)[8], short8 (&h)[2][4]) {
        const int e0 = t * 32;
        int nR[2], nC[2];
#pragma unroll
        for (int m = 0; m < 2; ++m) {
            nR[m] = eidx[e0 + m * 16 + l16];
            nC[m] = eidx[N_EDGES + e0 + m * 16 + l16];
        }
#pragma unroll
        for (int m = 0; m < 2; ++m)
#pragma unroll
            for (int r = 0; r < 4; ++r)
                nsv[m * 4 + r] = eidx[e0 + m * 16 + q * 4 + r];   // L1-hot reload
#pragma unroll
        for (int m = 0; m < 2; ++m)
#pragma unroll
            for (int kk = 0; kk < 4; ++kk) {
                int node = (kk >= 2) ? nC[m] : nR[m];
                if (XB) {
                    h[m][kk] = *(const short8*)(xbf + (size_t)node * DIM_IN + (kk & 1) * 32 + q * 8);
                } else {
                    const float* p = x + (size_t)node * DIM_IN + (kk & 1) * 32 + q * 8;
                    float4 v0 = *(const float4*)p;
                    float4 v1 = *(const float4*)(p + 4);
                    U8 tt;
                    tt.u.x = cvt_pk_bf16(v0.x, v0.y);
                    tt.u.y = cvt_pk_bf16(v0.z, v0.w);
                    tt.u.z = cvt_pk_bf16(v1.x, v1.y);
                    tt.u.w = cvt_pk_bf16(v1.z, v1.w);
                    h[m][kk] = tt.s;
                }
            }
    };

    int tile = gwid;
    int ns[8];
    short8 hfr[2][4];
    load_tile(tile, ns, hfr);

    while (true) {
        // ---- layers 0,1: H^T = softplus(W^T H^T + b), weights from LDS ----
#pragma unroll
        for (int L = 0; L < 2; ++L) {
            const float* bias = L ? b1 : b0;
            unsigned d[2][8][2];
#pragma unroll
            for (int ti = 0; ti < 8; ++ti) {
                f32x4 bb = *(const f32x4*)(bias + ti * 16 + q * 4);  // bias on row dim
                f32x4 a0 = bb, a1 = bb;
                const unsigned short* rowb = lw + ((L * 128 + ti * 16 + l16) * WROW);
                short8 wf[4];
#pragma unroll
                for (int kk = 0; kk < 4; ++kk)
                    wf[kk] = *(const short8*)(rowb + ((kk * 4 + q) ^ sx) * 8); // ds_read_b128
#pragma unroll
                for (int kk = 0; kk < 4; ++kk) {
                    a0 = __builtin_amdgcn_mfma_f32_16x16x32_bf16(wf[kk], hfr[0][kk], a0, 0, 0, 0);
                    a1 = __builtin_amdgcn_mfma_f32_16x16x32_bf16(wf[kk], hfr[1][kk], a1, 0, 0, 0);
                }
                // per-ti epilogue keeps acc liveness at 8 VGPRs
                d[0][ti][0] = sp2(a0[0], a0[1]);
                d[0][ti][1] = sp2(a0[2], a0[3]);
                d[1][ti][0] = sp2(a1[0], a1[1]);
                d[1][ti][1] = sp2(a1[2], a1[3]);
            }
            // next-layer frags: pure register renaming (weights carry pi)
#pragma unroll
            for (int m = 0; m < 2; ++m)
#pragma unroll
                for (int kk = 0; kk < 4; ++kk) {
                    U8 t;
                    t.u.x = d[m][2 * kk][0];
                    t.u.y = d[m][2 * kk][1];
                    t.u.z = d[m][2 * kk + 1][0];
                    t.u.w = d[m][2 * kk + 1][1];
                    hfr[m][kk] = t.s;
                }
        }

        // ---- layer 2 (un-flipped): O = H W2 + b2; weights from global (L1-hot)
        f32x4 acc[4][2];
#pragma unroll
        for (int ti = 0; ti < 4; ++ti) {
            float bv = b2[ti * 16 + l16];                    // bias on col dim
            f32x4 a0 = (f32x4){bv, bv, bv, bv};
            f32x4 a1 = a0;
            const unsigned short* Wp = Wt2 + (ti * 16 + l16) * WROW + q * 8;
            short8 wf[4];
#pragma unroll
            for (int kk = 0; kk < 4; ++kk)
                wf[kk] = *(const short8*)(Wp + kk * 32);
#pragma unroll
            for (int kk = 0; kk < 4; ++kk) {
                a0 = __builtin_amdgcn_mfma_f32_16x16x32_bf16(hfr[0][kk], wf[kk], a0, 0, 0, 0);
                a1 = __builtin_amdgcn_mfma_f32_16x16x32_bf16(hfr[1][kk], wf[kk], a1, 0, 0, 0);
            }
            acc[ti][0] = a0;
            acc[ti][1] = a1;
        }

        // ---- prefetch next tile BEFORE the atomic burst (vmcnt is in-order:
        // anything issued after the atomics waits on all atomic acks) ----
        const int nxt = tile + NWAVES;
        const bool more = (nxt < NTILES);        // wave-uniform
        int ns2[8];
        short8 hfr2[2][4];
        if (more) load_tile(nxt, ns2, hfr2);

        // ---- terminal atomic burst: fire-and-forget. each instruction covers
        // full 64B sectors (quad-uniform node, l16 lanes contiguous). ----
#pragma unroll
        for (int ti = 0; ti < 4; ++ti)
#pragma unroll
            for (int r = 0; r < 4; ++r) {
                atomicAdd(out + (size_t)ns[r] * DIM_OUT + ti * 16 + l16, acc[ti][0][r]);
                atomicAdd(out + (size_t)ns[4 + r] * DIM_OUT + ti * 16 + l16, acc[ti][1][r]);
            }

        if (!more) break;
        tile = nxt;
#pragma unroll
        for (int i = 0; i < 8; ++i) ns[i] = ns2[i];
#pragma unroll
        for (int m = 0; m < 2; ++m)
#pragma unroll
            for (int kk = 0; kk < 4; ++kk)
                hfr[m][kk] = hfr2[m][kk];
    }
}

extern "C" void kernel_launch(void* const* d_in, const int* in_sizes, int n_in,
                              void* d_out, int out_size, void* d_ws, size_t ws_size,
                              hipStream_t stream) {
    const float* x  = (const float*)d_in[0];
    const int*   ei = (const int*)d_in[1];
    const float* W0 = (const float*)d_in[2];
    const float* b0 = (const float*)d_in[3];
    const float* W1 = (const float*)d_in[4];
    const float* b1 = (const float*)d_in[5];
    const float* W2 = (const float*)d_in[6];
    const float* b2 = (const float*)d_in[7];
    float* out = (float*)d_out;

    unsigned short* wt = (unsigned short*)d_ws;
    const size_t WT_BYTES = (size_t)320 * WROW * sizeof(unsigned short);  // 81920 (256-aligned)
    unsigned short* xbf = (unsigned short*)((char*)d_ws + WT_BYTES);
    const size_t need = WT_BYTES + (size_t)N_NODES * DIM_IN * sizeof(unsigned short); // ~6.5 MB

    hipMemsetAsync(out, 0, (size_t)N_NODES * DIM_OUT * sizeof(float), stream);

    if (ws_size >= need) {
        prep_all<true><<<(N_NODES * DIM_IN / 4 + 255) / 256, 256, 0, stream>>>(
            x, W0, W1, W2, wt, xbf);
        edge_mlp_mfma<true><<<GRID, 512, 0, stream>>>(
            x, xbf, ei, wt, b0, b1, b2, out);
    } else {
        // fallback: weights-only prep, f32 x gather
        prep_all<false><<<(320 * WROW + 255) / 256, 256, 0, stream>>>(
            x, W0, W1, W2, wt, nullptr);
        edge_mlp_mfma<false><<<GRID, 512, 0, stream>>>(
            x, nullptr, ei, wt, b0, b1, b2, out);
    }
}

// Round 9
// 281.944 us; speedup vs baseline: 1.8056x; 1.1111x over previous
//
#include <hip/hip_runtime.h>
#include <math.h>

#define N_NODES 50000
#define N_EDGES 800000
#define DIM_IN 64
#define DIM_HID 128
#define DIM_OUT 64
#define WROW 128                // bf16 per weight row: 256B (XOR swizzle handles banks)
#define NTILES (N_EDGES / 32)   // 25000 wave-tiles of 32 edges
#define GRID 512                // 2 blocks/CU * 256 CU
#define NWAVES (GRID * 8)       // 4096 persistent waves

typedef __attribute__((ext_vector_type(8))) short short8;   // 8 bf16 (4 VGPRs)
typedef __attribute__((ext_vector_type(4))) float f32x4;    // MFMA accumulator

union U8 { uint4 u; short8 s; };

// RTNE float->bf16 (inputs finite) -- software path, used only in weight prep
__device__ __forceinline__ unsigned short f2bf(float f) {
    unsigned u = __float_as_uint(f);
    return (unsigned short)((u + 0x7fffu + ((u >> 16) & 1u)) >> 16);
}

// gfx950 has NO cvt_pk_bf16 builtin (learn_hip m240). Single VOP3 via asm.
// lo = a, hi = b; RTNE (default round mode) == the software f2bf path.
__device__ __forceinline__ unsigned cvt_pk_bf16(float a, float b) {
    unsigned d;
    asm("v_cvt_pk_bf16_f32 %0, %1, %2" : "=v"(d) : "v"(a), "v"(b));
    return d;
}

__device__ __forceinline__ float exp2_fast(float a) {
#if __has_builtin(__builtin_amdgcn_exp2f)
    return __builtin_amdgcn_exp2f(a);
#else
    return __expf(a * 0.69314718f);
#endif
}

// softplus(x) = max(x,0) + log1p(exp(-|x|)); log1p(z) ~ z*(1 + z*(-0.5 + z*(A + z*B)))
// cubic fit on z in (0,1], max abs err ~1.5e-3 (below bf16 quantization of H)
__device__ __forceinline__ unsigned sp2(float x0, float x1) {
    const float L2E = 1.44269504f;
    float z0 = exp2_fast(-fabsf(x0) * L2E);
    float z1 = exp2_fast(-fabsf(x1) * L2E);
    float p0 = fmaf(fmaf(fmaf(-0.1011458f, z0, 0.2942925f), z0, -0.5f), z0, 1.0f) * z0;
    float p1 = fmaf(fmaf(fmaf(-0.1011458f, z1, 0.2942925f), z1, -0.5f), z1, 1.0f) * z1;
    return cvt_pk_bf16(fmaxf(x0, 0.0f) + p0, fmaxf(x1, 0.0f) + p1);
}

// Prep: convert x to a bf16 table (optional) + build bf16 W^T [320][128] table
// (layers 1,2 carry the K-permutation pi matching the MFMA C-layout -> frag
// renaming). Output zeroing is a separate hipMemsetAsync (DMA path).
template <bool DO_XBF>
__global__ void prep_all(const float* __restrict__ x,
                         const float* __restrict__ W0,
                         const float* __restrict__ W1,
                         const float* __restrict__ W2,
                         unsigned short* __restrict__ wt,
                         unsigned short* __restrict__ xbf) {
    int i = blockIdx.x * blockDim.x + threadIdx.x;

    if (DO_XBF && i < (N_NODES * DIM_IN / 4)) {      // 800000 float4 -> uint2 bf16
        float4 v = *((const float4*)x + i);
        uint2 p;
        p.x = cvt_pk_bf16(v.x, v.y);
        p.y = cvt_pk_bf16(v.z, v.w);
        *((uint2*)xbf + i) = p;
    }

    if (i < 320 * WROW) {                            // 40960 weight elements
        int row = i >> 7, s = i & 127;
        float v;
        int f = ((s >> 5) << 5) | (((s & 7) >> 2) << 4) | (((s >> 3) & 3) << 2) | (s & 3);
        if (row < 128)      v = W0[s * DIM_HID + row];          // layer 0: natural k
        else if (row < 256) v = W1[f * DIM_HID + (row - 128)];  // layer 1: permuted k
        else                v = W2[f * DIM_OUT + (row - 256)];  // layer 2: permuted k
        wt[i] = f2bf(v);
    }
}

// PERSISTENT edge-MLP. Layers 0,1 flipped: H^T = softplus(W^T H^T + b) via
// mfma(A=weight, B=activation). Layer 2 un-flipped: O = H W2 + b2.
//
// R8 de-confounded: __launch_bounds__ 2nd arg is min BLOCKS/CU (CUDA
// semantics -- R6/R7/R8 VGPR collapse 32/40/64 matches block-based caps, not
// wave-based). (512,4) meant 32 waves/CU -> 64-reg cap -> 440MB scratch spill.
// THIS ROUND: (512,2) -> 2 blocks/CU (the 64KB-LDS limit anyway) -> 128-reg
// cap, the only cap that has never spilled this kernel (~100-reg peak).
// Persistent loop WITHOUT cross-tile prefetch (that +40 live regs is what
// pushed R8 past its cap). Stage L0+L1 once, one barrier, then each wave
// independently grid-strides ~6 tiles of 32 edges -- no barriers, no
// re-staging, waves drift out of phase so shared pipes interleave.
template <bool XB>
__global__ __launch_bounds__(512, 2)
void edge_mlp_mfma(const float* __restrict__ x,
                   const unsigned short* __restrict__ xbf,
                   const int* __restrict__ eidx,
                   const unsigned short* __restrict__ wt,
                   const float* __restrict__ b0,
                   const float* __restrict__ b1,
                   const float* __restrict__ b2,
                   float* __restrict__ out) {
    __shared__ unsigned short lw[256 * WROW];   // 65,536 B: L0+L1 tables

    const int lane = threadIdx.x & 63;
    const int w    = threadIdx.x >> 6;          // 0..7
    const int l16  = lane & 15;
    const int q    = lane >> 4;
    const int sx   = l16 & 7;                   // read-side swizzle key
    const int gwid = blockIdx.x * 8 + w;        // 0..4095

    // stage L0+L1 (rows 0..255): 4096 uint4, swizzled: 16B-slot col -> col^(row&7)
    {
        const uint4* src = (const uint4*)wt;
        uint4* dst = (uint4*)lw;
#pragma unroll
        for (int it = 0; it < 8; ++it) {
            int i = threadIdx.x + it * 512;
            int row = i >> 4, col = i & 15;
            dst[(row << 4) | (col ^ (row & 7))] = src[i];
        }
    }
    __syncthreads();   // the ONLY barrier in this kernel

    const unsigned short* Wt2 = wt + 256 * WROW;   // L2 table: global, L1-hot

    for (int tile = gwid; tile < NTILES; tile += NWAVES) {
        const int e0 = tile * 32;

        // edge indices + layer-0 B-frags B(k=kk*32+q*8+j, edge=m*16+l16)
        int nodeR[2], nodeC[2];
#pragma unroll
        for (int m = 0; m < 2; ++m) {
            nodeR[m] = eidx[e0 + m * 16 + l16];
            nodeC[m] = eidx[N_EDGES + e0 + m * 16 + l16];
        }
        int ns[8];
#pragma unroll
        for (int m = 0; m < 2; ++m)
#pragma unroll
            for (int r = 0; r < 4; ++r)
                ns[m * 4 + r] = eidx[e0 + m * 16 + q * 4 + r];   // L1-hot reload

        short8 hfr[2][4];
#pragma unroll
        for (int m = 0; m < 2; ++m)
#pragma unroll
            for (int kk = 0; kk < 4; ++kk) {
                int node = (kk >= 2) ? nodeC[m] : nodeR[m];
                if (XB) {
                    hfr[m][kk] = *(const short8*)(xbf + (size_t)node * DIM_IN + (kk & 1) * 32 + q * 8);
                } else {
                    const float* p = x + (size_t)node * DIM_IN + (kk & 1) * 32 + q * 8;
                    float4 v0 = *(const float4*)p;
                    float4 v1 = *(const float4*)(p + 4);
                    U8 t;
                    t.u.x = cvt_pk_bf16(v0.x, v0.y);
                    t.u.y = cvt_pk_bf16(v0.z, v0.w);
                    t.u.z = cvt_pk_bf16(v1.x, v1.y);
                    t.u.w = cvt_pk_bf16(v1.z, v1.w);
                    hfr[m][kk] = t.s;
                }
            }

        // ---- layers 0,1: H^T = softplus(W^T H^T + b), weights from LDS ----
#pragma unroll
        for (int L = 0; L < 2; ++L) {
            const float* bias = L ? b1 : b0;
            unsigned d[2][8][2];
#pragma unroll
            for (int ti = 0; ti < 8; ++ti) {
                f32x4 bb = *(const f32x4*)(bias + ti * 16 + q * 4);  // bias on row dim
                f32x4 a0 = bb, a1 = bb;
                const unsigned short* rowb = lw + ((L * 128 + ti * 16 + l16) * WROW);
                short8 wf[4];
#pragma unroll
                for (int kk = 0; kk < 4; ++kk)
                    wf[kk] = *(const short8*)(rowb + ((kk * 4 + q) ^ sx) * 8); // ds_read_b128
#pragma unroll
                for (int kk = 0; kk < 4; ++kk) {
                    a0 = __builtin_amdgcn_mfma_f32_16x16x32_bf16(wf[kk], hfr[0][kk], a0, 0, 0, 0);
                    a1 = __builtin_amdgcn_mfma_f32_16x16x32_bf16(wf[kk], hfr[1][kk], a1, 0, 0, 0);
                }
                // per-ti epilogue keeps acc liveness at 8 VGPRs
                d[0][ti][0] = sp2(a0[0], a0[1]);
                d[0][ti][1] = sp2(a0[2], a0[3]);
                d[1][ti][0] = sp2(a1[0], a1[1]);
                d[1][ti][1] = sp2(a1[2], a1[3]);
            }
            // next-layer frags: pure register renaming (weights carry pi)
#pragma unroll
            for (int m = 0; m < 2; ++m)
#pragma unroll
                for (int kk = 0; kk < 4; ++kk) {
                    U8 t;
                    t.u.x = d[m][2 * kk][0];
                    t.u.y = d[m][2 * kk][1];
                    t.u.z = d[m][2 * kk + 1][0];
                    t.u.w = d[m][2 * kk + 1][1];
                    hfr[m][kk] = t.s;
                }
        }

        // ---- layer 2 (un-flipped): O = H W2 + b2; weights from global (L1-hot)
        f32x4 acc[4][2];
#pragma unroll
        for (int ti = 0; ti < 4; ++ti) {
            float bv = b2[ti * 16 + l16];                    // bias on col dim
            f32x4 a0 = (f32x4){bv, bv, bv, bv};
            f32x4 a1 = a0;
            const unsigned short* Wp = Wt2 + (ti * 16 + l16) * WROW + q * 8;
            short8 wf[4];
#pragma unroll
            for (int kk = 0; kk < 4; ++kk)
                wf[kk] = *(const short8*)(Wp + kk * 32);
#pragma unroll
            for (int kk = 0; kk < 4; ++kk) {
                a0 = __builtin_amdgcn_mfma_f32_16x16x32_bf16(hfr[0][kk], wf[kk], a0, 0, 0, 0);
                a1 = __builtin_amdgcn_mfma_f32_16x16x32_bf16(hfr[1][kk], wf[kk], a1, 0, 0, 0);
            }
            acc[ti][0] = a0;
            acc[ti][1] = a1;
        }

        // ---- terminal atomic burst: fire-and-forget. each instruction covers
        // full 64B sectors (quad-uniform node, l16 lanes contiguous). ----
#pragma unroll
        for (int ti = 0; ti < 4; ++ti)
#pragma unroll
            for (int r = 0; r < 4; ++r) {
                atomicAdd(out + (size_t)ns[r] * DIM_OUT + ti * 16 + l16, acc[ti][0][r]);
                atomicAdd(out + (size_t)ns[4 + r] * DIM_OUT + ti * 16 + l16, acc[ti][1][r]);
            }
    }
}

extern "C" void kernel_launch(void* const* d_in, const int* in_sizes, int n_in,
                              void* d_out, int out_size, void* d_ws, size_t ws_size,
                              hipStream_t stream) {
    const float* x  = (const float*)d_in[0];
    const int*   ei = (const int*)d_in[1];
    const float* W0 = (const float*)d_in[2];
    const float* b0 = (const float*)d_in[3];
    const float* W1 = (const float*)d_in[4];
    const float* b1 = (const float*)d_in[5];
    const float* W2 = (const float*)d_in[6];
    const float* b2 = (const float*)d_in[7];
    float* out = (float*)d_out;

    unsigned short* wt = (unsigned short*)d_ws;
    const size_t WT_BYTES = (size_t)320 * WROW * sizeof(unsigned short);  // 81920 (256-aligned)
    unsigned short* xbf = (unsigned short*)((char*)d_ws + WT_BYTES);
    const size_t need = WT_BYTES + (size_t)N_NODES * DIM_IN * sizeof(unsigned short); // ~6.5 MB

    hipMemsetAsync(out, 0, (size_t)N_NODES * DIM_OUT * sizeof(float), stream);

    if (ws_size >= need) {
        prep_all<true><<<(N_NODES * DIM_IN / 4 + 255) / 256, 256, 0, stream>>>(
            x, W0, W1, W2, wt, xbf);
        edge_mlp_mfma<true><<<GRID, 512, 0, stream>>>(
            x, xbf, ei, wt, b0, b1, b2, out);
    } else {
        // fallback: weights-only prep, f32 x gather
        prep_all<false><<<(320 * WROW + 255) / 256, 256, 0, stream>>>(
            x, W0, W1, W2, wt, nullptr);
        edge_mlp_mfma<false><<<GRID, 512, 0, stream>>>(
            x, nullptr, ei, wt, b0, b1, b2, out);
    }
}

// Round 10
// 272.705 us; speedup vs baseline: 1.8668x; 1.0339x over previous
//
#include <hip/hip_runtime.h>
#include <math.h>

#define N_NODES 50000
#define N_EDGES 800000
#define DIM_IN 64
#define DIM_HID 128
#define DIM_OUT 64
#define WROW 128                // bf16 per weight row: 256B
#define NTILES (N_EDGES / 32)   // 25000 wave-tiles of 32 edges
#define GRID 512                // 2 blocks/CU * 256 CU
#define NWAVES (GRID * 8)       // 4096 persistent waves

typedef __attribute__((ext_vector_type(8))) short short8;   // 8 bf16 (4 VGPRs)
typedef __attribute__((ext_vector_type(4))) float f32x4;    // MFMA accumulator

union U8 { uint4 u; short8 s; };

// RTNE float->bf16 (inputs finite) -- software path, used only in weight prep
__device__ __forceinline__ unsigned short f2bf(float f) {
    unsigned u = __float_as_uint(f);
    return (unsigned short)((u + 0x7fffu + ((u >> 16) & 1u)) >> 16);
}

// gfx950 has NO cvt_pk_bf16 builtin (learn_hip m240). Single VOP3 via asm.
__device__ __forceinline__ unsigned cvt_pk_bf16(float a, float b) {
    unsigned d;
    asm("v_cvt_pk_bf16_f32 %0, %1, %2" : "=v"(d) : "v"(a), "v"(b));
    return d;
}

__device__ __forceinline__ float exp2_fast(float a) {
#if __has_builtin(__builtin_amdgcn_exp2f)
    return __builtin_amdgcn_exp2f(a);
#else
    return __expf(a * 0.69314718f);
#endif
}

// softplus(x) = max(x,0) + log1p(exp(-|x|)); cubic log1p fit, err ~1.5e-3
__device__ __forceinline__ unsigned sp2(float x0, float x1) {
    const float L2E = 1.44269504f;
    float z0 = exp2_fast(-fabsf(x0) * L2E);
    float z1 = exp2_fast(-fabsf(x1) * L2E);
    float p0 = fmaf(fmaf(fmaf(-0.1011458f, z0, 0.2942925f), z0, -0.5f), z0, 1.0f) * z0;
    float p1 = fmaf(fmaf(fmaf(-0.1011458f, z1, 0.2942925f), z1, -0.5f), z1, 1.0f) * z1;
    return cvt_pk_bf16(fmaxf(x0, 0.0f) + p0, fmaxf(x1, 0.0f) + p1);
}

// Prep: convert x to bf16 table (optional) + bf16 W^T [320][128] (layers 1,2
// carry the K-permutation pi for the C-layout->frag renaming).
template <bool DO_XBF>
__global__ void prep_all(const float* __restrict__ x,
                         const float* __restrict__ W0,
                         const float* __restrict__ W1,
                         const float* __restrict__ W2,
                         unsigned short* __restrict__ wt,
                         unsigned short* __restrict__ xbf) {
    int i = blockIdx.x * blockDim.x + threadIdx.x;

    if (DO_XBF && i < (N_NODES * DIM_IN / 4)) {
        float4 v = *((const float4*)x + i);
        uint2 p;
        p.x = cvt_pk_bf16(v.x, v.y);
        p.y = cvt_pk_bf16(v.z, v.w);
        *((uint2*)xbf + i) = p;
    }

    if (i < 320 * WROW) {
        int row = i >> 7, s = i & 127;
        float v;
        int f = ((s >> 5) << 5) | (((s & 7) >> 2) << 4) | (((s >> 3) & 3) << 2) | (s & 3);
        if (row < 128)      v = W0[s * DIM_HID + row];          // layer 0: natural k
        else if (row < 256) v = W1[f * DIM_HID + (row - 128)];  // layer 1: permuted k
        else                v = W2[f * DIM_OUT + (row - 256)];  // layer 2: permuted k
        wt[i] = f2bf(v);
    }
}

// PERSISTENT edge-MLP, vmcnt-decoupled pipeline.
// R9 finding: floor ~206us invariant under fetch/atomic/weight/occupancy/
// barrier diets. Remaining unremoved cost: every in-loop load-use wait
// transitively drains the previous tile's 32 atomic acks (vmcnt retires in
// ISSUE order) plus the naked gather chain at each tile top. This round:
//  - biases + L0 + L2 weights in LDS (50.4KB static): their reads are
//    ds_read (lgkm counter) -- immune to the atomic vmcnt queue;
//  - L1 weights from global, placed mid-pipeline (~1600cy after the previous
//    atomic burst, so acks are retired before their waitcnt);
//  - tile boundary issue order: next-tile node loads -> current ns loads ->
//    next-tile gathers -> atomics. In-order vmcnt then lets atomics issue
//    while gathers fly, and next-L0's hfr wait tolerates flying atomics.
// (512,2): 2 blocks/CU, 16 waves/CU, 128-reg cap (the only never-spilled cap).
template <bool XB>
__global__ __launch_bounds__(512, 2)
void edge_mlp_mfma(const float* __restrict__ x,
                   const unsigned short* __restrict__ xbf,
                   const int* __restrict__ eidx,
                   const unsigned short* __restrict__ wt,
                   const float* __restrict__ b0,
                   const float* __restrict__ b1,
                   const float* __restrict__ b2,
                   float* __restrict__ out) {
    __shared__ unsigned short lw0[128 * WROW];  // 32KB: L0 weights, XOR-swizzled
    __shared__ unsigned short lw2[64 * WROW];   // 16KB: L2 weights, XOR-swizzled
    __shared__ float lb[128 + 128 + 64];        // 1.25KB: b0|b1|b2

    const int lane = threadIdx.x & 63;
    const int w    = threadIdx.x >> 6;          // 0..7
    const int l16  = lane & 15;
    const int q    = lane >> 4;
    const int sx   = l16 & 7;                   // read-side swizzle key
    const int gwid = blockIdx.x * 8 + w;        // 0..4095

    // ---- one-time staging ----
    {
        const uint4* s0 = (const uint4*)wt;                  // rows 0..127
        uint4* d0 = (uint4*)lw0;
#pragma unroll
        for (int it = 0; it < 4; ++it) {
            int i = threadIdx.x + it * 512;                  // 0..2047
            int row = i >> 4, col = i & 15;
            d0[(row << 4) | (col ^ (row & 7))] = s0[i];
        }
        const uint4* s2 = (const uint4*)(wt + 256 * WROW);   // rows 256..319
        uint4* d2 = (uint4*)lw2;
#pragma unroll
        for (int it = 0; it < 2; ++it) {
            int i = threadIdx.x + it * 512;                  // 0..1023
            int row = i >> 4, col = i & 15;
            d2[(row << 4) | (col ^ (row & 7))] = s2[i];
        }
        int t = threadIdx.x;
        if (t < 128)      lb[t] = b0[t];
        else if (t < 256) lb[t] = b1[t - 128];
        else if (t < 320) lb[t] = b2[t - 256];
    }
    __syncthreads();   // the ONLY barrier

    const unsigned short* Wt1 = wt + 128 * WROW;   // L1 weights: global (TCP/L2-hot)

    // gather loader: layer-0 B-frags B(k=kk*32+q*8+j, edge=m*16+l16)
    auto gather = [&](int e0, const int (&nR)[2], const int (&nC)[2], short8 (&h)[2][4]) {
#pragma unroll
        for (int m = 0; m < 2; ++m)
#pragma unroll
            for (int kk = 0; kk < 4; ++kk) {
                int node = (kk >= 2) ? nC[m] : nR[m];
                if (XB) {
                    h[m][kk] = *(const short8*)(xbf + (size_t)node * DIM_IN + (kk & 1) * 32 + q * 8);
                } else {
                    const float* p = x + (size_t)node * DIM_IN + (kk & 1) * 32 + q * 8;
                    float4 v0 = *(const float4*)p;
                    float4 v1 = *(const float4*)(p + 4);
                    U8 t;
                    t.u.x = cvt_pk_bf16(v0.x, v0.y);
                    t.u.y = cvt_pk_bf16(v0.z, v0.w);
                    t.u.z = cvt_pk_bf16(v1.x, v1.y);
                    t.u.w = cvt_pk_bf16(v1.z, v1.w);
                    h[m][kk] = t.s;
                }
            }
    };

    int tile = gwid;
    short8 hfr[2][4];
    {   // prologue: gather first tile
        const int e0 = tile * 32;
        int nR[2], nC[2];
#pragma unroll
        for (int m = 0; m < 2; ++m) {
            nR[m] = eidx[e0 + m * 16 + l16];
            nC[m] = eidx[N_EDGES + e0 + m * 16 + l16];
        }
        gather(e0, nR, nC, hfr);
    }

    while (true) {
        // ---- layers 0,1: H^T = softplus(W^T H^T + b) ----
#pragma unroll
        for (int L = 0; L < 2; ++L) {
            unsigned d[2][8][2];
#pragma unroll
            for (int ti = 0; ti < 8; ++ti) {
                f32x4 bb = *(const f32x4*)(lb + L * 128 + ti * 16 + q * 4);  // ds_read
                f32x4 a0 = bb, a1 = bb;
                short8 wf[4];
                if (L == 0) {
                    const unsigned short* rowb = lw0 + (ti * 16 + l16) * WROW;
#pragma unroll
                    for (int kk = 0; kk < 4; ++kk)
                        wf[kk] = *(const short8*)(rowb + ((kk * 4 + q) ^ sx) * 8); // ds_read_b128
                } else {
                    // global, mid-pipeline: previous atomics' acks already retired
                    const unsigned short* Wp = Wt1 + (ti * 16 + l16) * WROW + q * 8;
#pragma unroll
                    for (int kk = 0; kk < 4; ++kk)
                        wf[kk] = *(const short8*)(Wp + kk * 32);
                }
#pragma unroll
                for (int kk = 0; kk < 4; ++kk) {
                    a0 = __builtin_amdgcn_mfma_f32_16x16x32_bf16(wf[kk], hfr[0][kk], a0, 0, 0, 0);
                    a1 = __builtin_amdgcn_mfma_f32_16x16x32_bf16(wf[kk], hfr[1][kk], a1, 0, 0, 0);
                }
                d[0][ti][0] = sp2(a0[0], a0[1]);
                d[0][ti][1] = sp2(a0[2], a0[3]);
                d[1][ti][0] = sp2(a1[0], a1[1]);
                d[1][ti][1] = sp2(a1[2], a1[3]);
            }
            // next-layer frags: pure register renaming (weights carry pi)
#pragma unroll
            for (int m = 0; m < 2; ++m)
#pragma unroll
                for (int kk = 0; kk < 4; ++kk) {
                    U8 t;
                    t.u.x = d[m][2 * kk][0];
                    t.u.y = d[m][2 * kk][1];
                    t.u.z = d[m][2 * kk + 1][0];
                    t.u.w = d[m][2 * kk + 1][1];
                    hfr[m][kk] = t.s;
                }
        }

        // ---- layer 2: O = H W2 + b2 (weights+bias from LDS: lgkm only) ----
        f32x4 acc[4][2];
#pragma unroll
        for (int ti = 0; ti < 4; ++ti) {
            float bv = lb[256 + ti * 16 + l16];              // ds_read
            f32x4 a0 = (f32x4){bv, bv, bv, bv};
            f32x4 a1 = a0;
            const unsigned short* rowb = lw2 + (ti * 16 + l16) * WROW;
            short8 wf[4];
#pragma unroll
            for (int kk = 0; kk < 4; ++kk)
                wf[kk] = *(const short8*)(rowb + ((kk * 4 + q) ^ sx) * 8);   // ds_read_b128
#pragma unroll
            for (int kk = 0; kk < 4; ++kk) {
                a0 = __builtin_amdgcn_mfma_f32_16x16x32_bf16(hfr[0][kk], wf[kk], a0, 0, 0, 0);
                a1 = __builtin_amdgcn_mfma_f32_16x16x32_bf16(hfr[1][kk], wf[kk], a1, 0, 0, 0);
            }
            acc[ti][0] = a0;
            acc[ti][1] = a1;
        }

        // ---- tile boundary: issue-order choreography ----
        const int nxt = tile + NWAVES;
        const bool more = (nxt < NTILES);            // wave-uniform
        const int e0c = tile * 32;

        // (1) next-tile node indices (oldest in queue)
        int nR2[2], nC2[2];
        if (more) {
            const int e0n = nxt * 32;
#pragma unroll
            for (int m = 0; m < 2; ++m) {
                nR2[m] = eidx[e0n + m * 16 + l16];
                nC2[m] = eidx[N_EDGES + e0n + m * 16 + l16];
            }
        }
        // (2) current-tile scatter nodes (older than the gathers below ->
        //     their wait does NOT drain the gathers)
        int ns[8];
#pragma unroll
        for (int m = 0; m < 2; ++m)
#pragma unroll
            for (int r = 0; r < 4; ++r)
                ns[m * 4 + r] = eidx[e0c + m * 16 + q * 4 + r];   // L1-hot

        // (3) next-tile gathers (youngest loads; still flying when atomics issue)
        short8 hfr2[2][4];
        if (more) gather(nxt * 32, nR2, nC2, hfr2);

        // (4) atomic burst: quad-uniform node, l16 contiguous -> full 64B sectors
#pragma unroll
        for (int ti = 0; ti < 4; ++ti)
#pragma unroll
            for (int r = 0; r < 4; ++r) {
                atomicAdd(out + (size_t)ns[r] * DIM_OUT + ti * 16 + l16, acc[ti][0][r]);
                atomicAdd(out + (size_t)ns[4 + r] * DIM_OUT + ti * 16 + l16, acc[ti][1][r]);
            }

        if (!more) break;
        tile = nxt;
#pragma unroll
        for (int m = 0; m < 2; ++m)
#pragma unroll
            for (int kk = 0; kk < 4; ++kk)
                hfr[m][kk] = hfr2[m][kk];
    }
}

extern "C" void kernel_launch(void* const* d_in, const int* in_sizes, int n_in,
                              void* d_out, int out_size, void* d_ws, size_t ws_size,
                              hipStream_t stream) {
    const float* x  = (const float*)d_in[0];
    const int*   ei = (const int*)d_in[1];
    const float* W0 = (const float*)d_in[2];
    const float* b0 = (const float*)d_in[3];
    const float* W1 = (const float*)d_in[4];
    const float* b1 = (const float*)d_in[5];
    const float* W2 = (const float*)d_in[6];
    const float* b2 = (const float*)d_in[7];
    float* out = (float*)d_out;

    unsigned short* wt = (unsigned short*)d_ws;
    const size_t WT_BYTES = (size_t)320 * WROW * sizeof(unsigned short);  // 81920
    unsigned short* xbf = (unsigned short*)((char*)d_ws + WT_BYTES);
    const size_t need = WT_BYTES + (size_t)N_NODES * DIM_IN * sizeof(unsigned short); // ~6.5 MB

    hipMemsetAsync(out, 0, (size_t)N_NODES * DIM_OUT * sizeof(float), stream);

    if (ws_size >= need) {
        prep_all<true><<<(N_NODES * DIM_IN / 4 + 255) / 256, 256, 0, stream>>>(
            x, W0, W1, W2, wt, xbf);
        edge_mlp_mfma<true><<<GRID, 512, 0, stream>>>(
            x, xbf, ei, wt, b0, b1, b2, out);
    } else {
        // fallback: weights-only prep, f32 x gather
        prep_all<false><<<(320 * WROW + 255) / 256, 256, 0, stream>>>(
            x, W0, W1, W2, wt, nullptr);
        edge_mlp_mfma<false><<<GRID, 512, 0, stream>>>(
            x, nullptr, ei, wt, b0, b1, b2, out);
    }
}